// Round 1
// baseline (679.003 us; speedup 1.0000x reference)
//
#include <hip/hip_runtime.h>

#define I_DIM 17
#define H_DIM 128
#define T_DIM 19
#define B_DIM 32768
#define M_ROWS 64
#define NTHR 256
#define XI (T_DIM * I_DIM) /* 323 */

typedef __bf16 bf16x8 __attribute__((ext_vector_type(8)));
typedef float f32x4 __attribute__((ext_vector_type(4)));

union FragU { bf16x8 v; unsigned short s[8]; };

__device__ __forceinline__ unsigned short f2bf(float f) {
    union { float f; unsigned u; } x; x.f = f;
    unsigned r = x.u + 0x7fffu + ((x.u >> 16) & 1u);
    return (unsigned short)(r >> 16);
}
__device__ __forceinline__ float sigm(float v) {
    float e = __builtin_amdgcn_exp2f(-1.4426950408889634f * v);
    return __builtin_amdgcn_rcpf(1.0f + e);
}
__device__ __forceinline__ float tanh_(float v) {
    float e = __builtin_amdgcn_exp2f(-2.8853900817779268f * v);
    return 2.0f * __builtin_amdgcn_rcpf(1.0f + e) - 1.0f;
}

__global__ __launch_bounds__(NTHR, 1)
void flowlstm(const float* __restrict__ x, const float* __restrict__ W_ih,
              const float* __restrict__ W_hh, const float* __restrict__ b_ih,
              const float* __restrict__ b_hh, const float* __restrict__ W_out,
              const float* __restrict__ b_out, float* __restrict__ out)
{
    // LDS: W_hh bf16 [512][128] (swizzled)  = 131072 B
    //      h    bf16 [64][128]  (swizzled)  =  16384 B
    //      x_t  bf16 2x[64][32] (swizzled)  =   8192 B
    __shared__ __align__(16) unsigned char smem[155648];
    unsigned char* Wl = smem;
    unsigned char* Hl = smem + 131072;
    unsigned char* Xl = smem + 147456;

    const int tid  = threadIdx.x;
    const int w    = tid >> 6;   // wave id 0..3
    const int lane = tid & 63;
    const int l15  = lane & 15;
    const int q    = lane >> 4;
    const int b0   = blockIdx.x * M_ROWS;

    // ---- stage W_hh -> LDS as bf16, row-XOR-swizzled (G4) ----
    for (int e = tid; e < 512 * 128; e += NTHR) {
        int n = e >> 7, k = e & 127;
        unsigned off = ((unsigned)(n * 256 + k * 2)) ^ (((unsigned)(n & 7)) << 4);
        *(unsigned short*)(Wl + off) = f2bf(W_hh[e]);
    }
    for (int e = tid; e < 4096; e += NTHR) ((unsigned*)Hl)[e] = 0u; // h0 = 0
    for (int e = tid; e < 2048; e += NTHR) ((unsigned*)Xl)[e] = 0u; // zero K-pad

    // ---- W_ih B-fragments in registers (K padded 17->32 with zeros) ----
    bf16x8 wih[8];
    #pragma unroll
    for (int nt = 0; nt < 8; ++nt) {
        int n = (nt >> 1) * 128 + 32 * w + 16 * (nt & 1) + l15;
        FragU fu;
        #pragma unroll
        for (int e = 0; e < 8; ++e) {
            int k = q * 8 + e;
            fu.s[e] = (k < I_DIM) ? f2bf(W_ih[n * I_DIM + k]) : (unsigned short)0;
        }
        wih[nt] = fu.v;
    }
    // ---- W_out B-fragments (N padded 17->32) ----
    bf16x8 wout[2][4];
    #pragma unroll
    for (int n2 = 0; n2 < 2; ++n2) {
        int o = n2 * 16 + l15;
        #pragma unroll
        for (int kk = 0; kk < 4; ++kk) {
            FragU fu;
            #pragma unroll
            for (int e = 0; e < 8; ++e) {
                int k = kk * 32 + q * 8 + e;
                fu.s[e] = (o < I_DIM) ? f2bf(W_out[o * H_DIM + k]) : (unsigned short)0;
            }
            wout[n2][kk] = fu.v;
        }
    }
    // ---- biases (b_ih + b_hh folded) ----
    float bias[4][2];
    #pragma unroll
    for (int g = 0; g < 4; ++g)
        #pragma unroll
        for (int hf = 0; hf < 2; ++hf) {
            int col = g * 128 + 32 * w + 16 * hf + l15;
            bias[g][hf] = b_ih[col] + b_hh[col];
        }
    const float bo0 = b_out[l15];
    const float bo1 = b_out[16];

    float cst[32];
    #pragma unroll
    for (int i = 0; i < 32; ++i) cst[i] = 0.0f;

    // x load mapping (t-invariant parts precomputed)
    int   xbase[5]; unsigned xoff[5]; bool xval[5];
    #pragma unroll
    for (int i = 0; i < 5; ++i) {
        int f = tid + i * NTHR;
        xval[i] = (f < M_ROWS * I_DIM);
        int row = f / I_DIM, k = f - row * I_DIM;
        if (!xval[i]) { row = 0; k = 0; }
        xbase[i] = (b0 + row) * XI + k;
        xoff[i]  = ((unsigned)(row * 64 + k * 2)) ^ (((unsigned)(row & 3)) << 4);
    }
    float xr[5];
    #pragma unroll
    for (int i = 0; i < 5; ++i) xr[i] = xval[i] ? x[xbase[i]] : 0.0f;

    for (int t = 0; t < T_DIM; ++t) {
        unsigned char* xb = Xl + (t & 1) * 4096;
        #pragma unroll
        for (int i = 0; i < 5; ++i)
            if (xval[i]) *(unsigned short*)(xb + xoff[i]) = f2bf(xr[i]);
        if (t + 1 < T_DIM) {           // prefetch next timestep into regs
            #pragma unroll
            for (int i = 0; i < 5; ++i)
                if (xval[i]) xr[i] = x[xbase[i] + (t + 1) * I_DIM];
        }
        __syncthreads();   // x_t staged, h_{t-1} staged

        f32x4 acc[4][8];
        #pragma unroll
        for (int mt = 0; mt < 4; ++mt)
            #pragma unroll
            for (int nt = 0; nt < 8; ++nt)
                acc[mt][nt] = (f32x4){0.f, 0.f, 0.f, 0.f};

        // x-projection K-step (K=32, zero-padded)
        #pragma unroll
        for (int mt = 0; mt < 4; ++mt) {
            int row = 16 * mt + l15;
            unsigned aoff = ((unsigned)(row * 64 + q * 16)) ^ (((unsigned)(row & 3)) << 4);
            bf16x8 a = *(const bf16x8*)(xb + aoff);
            #pragma unroll
            for (int nt = 0; nt < 8; ++nt)
                acc[mt][nt] = __builtin_amdgcn_mfma_f32_16x16x32_bf16(a, wih[nt], acc[mt][nt], 0, 0, 0);
        }
        // recurrent K-steps: gates += h_{t-1} @ W_hh^T
        #pragma unroll
        for (int kk = 0; kk < 4; ++kk) {
            bf16x8 bfr[8];
            #pragma unroll
            for (int nt = 0; nt < 8; ++nt) {
                int n = (nt >> 1) * 128 + 32 * w + 16 * (nt & 1) + l15;
                unsigned boff = ((unsigned)(n * 256 + kk * 64 + q * 16)) ^ (((unsigned)(n & 7)) << 4);
                bfr[nt] = *(const bf16x8*)(Wl + boff);
            }
            #pragma unroll
            for (int mt = 0; mt < 4; ++mt) {
                int row = 16 * mt + l15;
                unsigned aoff = ((unsigned)(row * 256 + kk * 64 + q * 16)) ^ (((unsigned)(row & 7)) << 4);
                bf16x8 a = *(const bf16x8*)(Hl + aoff);
                #pragma unroll
                for (int nt = 0; nt < 8; ++nt)
                    acc[mt][nt] = __builtin_amdgcn_mfma_f32_16x16x32_bf16(a, bfr[nt], acc[mt][nt], 0, 0, 0);
            }
        }
        // y_{t-1} = h_{t-1} @ W_out^T  (wave w does rows 16w..16w+15)
        if (t > 0) {
            f32x4 ya0 = {0.f,0.f,0.f,0.f}, ya1 = {0.f,0.f,0.f,0.f};
            #pragma unroll
            for (int kk = 0; kk < 4; ++kk) {
                int row = 16 * w + l15;
                unsigned aoff = ((unsigned)(row * 256 + kk * 64 + q * 16)) ^ (((unsigned)(row & 7)) << 4);
                bf16x8 a = *(const bf16x8*)(Hl + aoff);
                ya0 = __builtin_amdgcn_mfma_f32_16x16x32_bf16(a, wout[0][kk], ya0, 0, 0, 0);
                ya1 = __builtin_amdgcn_mfma_f32_16x16x32_bf16(a, wout[1][kk], ya1, 0, 0, 0);
            }
            #pragma unroll
            for (int r = 0; r < 4; ++r) {
                int row = 16 * w + q * 4 + r;
                size_t base = ((size_t)(b0 + row) * T_DIM + (t - 1)) * I_DIM;
                out[base + l15] = ya0[r] + bo0;
                if (l15 == 0) out[base + 16] = ya1[r] + bo1;
            }
        }
        // elementwise cell update (fp32; c in registers)
        float hv[32];
        #pragma unroll
        for (int mt = 0; mt < 4; ++mt)
            #pragma unroll
            for (int hf = 0; hf < 2; ++hf)
                #pragma unroll
                for (int r = 0; r < 4; ++r) {
                    int ci = mt * 8 + hf * 4 + r;
                    float ig = acc[mt][0 + hf][r] + bias[0][hf];
                    float fg = acc[mt][2 + hf][r] + bias[1][hf];
                    float gg = acc[mt][4 + hf][r] + bias[2][hf];
                    float og = acc[mt][6 + hf][r] + bias[3][hf];
                    float c  = sigm(fg) * cst[ci] + sigm(ig) * tanh_(gg);
                    cst[ci] = c;
                    hv[ci]  = sigm(og) * tanh_(c);
                }
        __syncthreads();   // everyone done reading h_{t-1}
        #pragma unroll
        for (int mt = 0; mt < 4; ++mt)
            #pragma unroll
            for (int hf = 0; hf < 2; ++hf)
                #pragma unroll
                for (int r = 0; r < 4; ++r) {
                    int ci  = mt * 8 + hf * 4 + r;
                    int row = 16 * mt + q * 4 + r;
                    int col = 32 * w + 16 * hf + l15;
                    unsigned off = ((unsigned)(row * 256 + col * 2)) ^ (((unsigned)(row & 7)) << 4);
                    *(unsigned short*)(Hl + off) = f2bf(hv[ci]);
                }
    }
    __syncthreads();
    // epilogue: y_{T-1}
    {
        f32x4 ya0 = {0.f,0.f,0.f,0.f}, ya1 = {0.f,0.f,0.f,0.f};
        #pragma unroll
        for (int kk = 0; kk < 4; ++kk) {
            int row = 16 * w + l15;
            unsigned aoff = ((unsigned)(row * 256 + kk * 64 + q * 16)) ^ (((unsigned)(row & 7)) << 4);
            bf16x8 a = *(const bf16x8*)(Hl + aoff);
            ya0 = __builtin_amdgcn_mfma_f32_16x16x32_bf16(a, wout[0][kk], ya0, 0, 0, 0);
            ya1 = __builtin_amdgcn_mfma_f32_16x16x32_bf16(a, wout[1][kk], ya1, 0, 0, 0);
        }
        #pragma unroll
        for (int r = 0; r < 4; ++r) {
            int row = 16 * w + q * 4 + r;
            size_t base = ((size_t)(b0 + row) * T_DIM + (T_DIM - 1)) * I_DIM;
            out[base + l15] = ya0[r] + bo0;
            if (l15 == 0) out[base + 16] = ya1[r] + bo1;
        }
    }
}

extern "C" void kernel_launch(void* const* d_in, const int* in_sizes, int n_in,
                              void* d_out, int out_size, void* d_ws, size_t ws_size,
                              hipStream_t stream) {
    const float* x     = (const float*)d_in[0];
    const float* W_ih  = (const float*)d_in[1];
    const float* W_hh  = (const float*)d_in[2];
    const float* b_ih  = (const float*)d_in[3];
    const float* b_hh  = (const float*)d_in[4];
    const float* W_out = (const float*)d_in[5];
    const float* b_out = (const float*)d_in[6];
    float* out = (float*)d_out;

    dim3 grid(B_DIM / M_ROWS), block(NTHR);
    flowlstm<<<grid, block, 0, stream>>>(x, W_ih, W_hh, b_ih, b_hh, W_out, b_out, out);
}

// Round 2
// 171.252 us; speedup vs baseline: 3.9649x; 3.9649x over previous
//
#include <hip/hip_runtime.h>

#define I_DIM 17
#define H_DIM 128
#define T_DIM 19
#define B_DIM 32768
#define M_ROWS 64
#define NTHR 1024
#define XI (T_DIM * I_DIM) /* 323 */

typedef __bf16 bf16x8 __attribute__((ext_vector_type(8)));
typedef float f32x4 __attribute__((ext_vector_type(4)));

union FragU { bf16x8 v; unsigned short s[8]; uint4 u; };

__device__ __forceinline__ unsigned short f2bf(float f) {
    union { float f; unsigned u; } x; x.f = f;
    unsigned r = x.u + 0x7fffu + ((x.u >> 16) & 1u);
    return (unsigned short)(r >> 16);
}
__device__ __forceinline__ float sigm(float v) {
    float e = __builtin_amdgcn_exp2f(-1.4426950408889634f * v);
    return __builtin_amdgcn_rcpf(1.0f + e);
}
__device__ __forceinline__ float tanh_(float v) {
    float e = __builtin_amdgcn_exp2f(-2.8853900817779268f * v);
    return 2.0f * __builtin_amdgcn_rcpf(1.0f + e) - 1.0f;
}

// LDS layout (bytes):
//   WhF: W_hh fragments, frag-ordered, 128 frags * 1024B = 131072
//   Hl : h tile [64][128] bf16, row stride 256B, XOR-swizzled    = 16384
//   WoF: W_out fragments, 8 frags * 1024B                        = 8192
//   Xl : x tile [64 rows][stride 80B] bf16 (K padded 17->32)     = 5120
#define LDS_H   131072
#define LDS_WOF 147456
#define LDS_X   155648
#define LDS_TOT 160768

__global__ __launch_bounds__(NTHR) void flowlstm(
    const float* __restrict__ x, const float* __restrict__ W_ih,
    const float* __restrict__ W_hh, const float* __restrict__ b_ih,
    const float* __restrict__ b_hh, const float* __restrict__ W_out,
    const float* __restrict__ b_out, float* __restrict__ out)
{
    __shared__ __align__(16) unsigned char smem[LDS_TOT];
    unsigned char* WhF = smem;
    unsigned char* Hl  = smem + LDS_H;
    unsigned char* WoF = smem + LDS_WOF;
    unsigned char* Xl  = smem + LDS_X;

    const int tid  = threadIdx.x;
    const int w    = tid >> 6;
    const int lane = tid & 63;
    const int l15  = lane & 15;
    const int q    = lane >> 4;
    const int wg   = w & 3;          // h-col group (32 cols)
    const int half = (w >> 2) & 1;   // 16-col half within group
    const int mth  = w >> 3;         // row half (32 rows)
    const int b0   = blockIdx.x * M_ROWS;

    // ---- stage W_hh fragments -> LDS (frag order => conflict-free b128 reads) ----
    #pragma unroll
    for (int i = 0; i < 8; ++i) {
        int lr = tid + i * NTHR;             // lane-row 0..8191
        int ln = lr & 63, f = lr >> 6;       // f = ((wg*2+half)*4+kk)*4+g
        int g = f & 3, kk = (f >> 2) & 3, hh = (f >> 4) & 1, wgs = f >> 5;
        int n  = g * 128 + wgs * 32 + hh * 16 + (ln & 15);
        int kb = kk * 32 + (ln >> 4) * 8;
        const float* s = W_hh + n * H_DIM + kb;
        FragU fu;
        #pragma unroll
        for (int e = 0; e < 8; ++e) fu.s[e] = f2bf(s[e]);
        *(uint4*)(WhF + lr * 16) = fu.u;
    }
    // ---- W_out fragments (N padded 17->32): 8 frags ----
    if (tid < 512) {
        int ln = tid & 63, f = tid >> 6;     // f = nt*4+kk
        int kk = f & 3, nt = f >> 2;
        int o  = nt * 16 + (ln & 15);
        int kb = kk * 32 + (ln >> 4) * 8;
        FragU fu;
        #pragma unroll
        for (int e = 0; e < 8; ++e)
            fu.s[e] = (o < I_DIM) ? f2bf(W_out[o * H_DIM + kb + e]) : (unsigned short)0;
        *(uint4*)(WoF + tid * 16) = fu.u;
    }
    // ---- zero h and x buffers ----
    #pragma unroll
    for (int i = 0; i < 4; ++i) ((unsigned*)Hl)[tid + i * NTHR] = 0u;
    for (int e = tid; e < 1280; e += NTHR) ((unsigned*)Xl)[e] = 0u;

    // ---- W_ih register fragments (K padded 17->32) ----
    bf16x8 wih[4];
    #pragma unroll
    for (int g = 0; g < 4; ++g) {
        int n = g * 128 + wg * 32 + half * 16 + l15;
        FragU fu;
        #pragma unroll
        for (int e = 0; e < 8; ++e) {
            int k = q * 8 + e;
            fu.s[e] = (k < I_DIM) ? f2bf(W_ih[n * I_DIM + k]) : (unsigned short)0;
        }
        wih[g] = fu.v;
    }
    // ---- biases (b_ih + b_hh folded, splatted into acc init) ----
    float bias[4];
    #pragma unroll
    for (int g = 0; g < 4; ++g) {
        int col = g * 128 + wg * 32 + half * 16 + l15;
        bias[g] = b_ih[col] + b_hh[col];
    }
    // y-phase constants (waves 0..7: tile (ymt, ynt))
    const int ymt = w >> 1, ynt = w & 1;
    const float ybo = (ynt == 0) ? b_out[l15] : b_out[16];

    // ---- x element mapping (2 elements/thread covers 64*17=1088) ----
    const int  f1   = tid;
    const int  row1 = f1 / I_DIM, k1 = f1 - row1 * I_DIM;
    const bool v2   = (tid < M_ROWS * I_DIM - NTHR);   // tid < 64
    const int  f2   = tid + NTHR;
    const int  row2 = v2 ? (f2 / I_DIM) : 0;
    const int  k2   = v2 ? (f2 - (f2 / I_DIM) * I_DIM) : 0;
    const size_t gb1 = (size_t)(b0 + row1) * XI + k1;
    const size_t gb2 = (size_t)(b0 + row2) * XI + k2;
    const int lo1 = row1 * 80 + k1 * 2;
    const int lo2 = row2 * 80 + k2 * 2;

    __syncthreads();                       // zeros done before x_0 staging
    *(unsigned short*)(Xl + lo1) = f2bf(x[gb1]);
    if (v2) *(unsigned short*)(Xl + lo2) = f2bf(x[gb2]);

    float cst[8];
    #pragma unroll
    for (int i = 0; i < 8; ++i) cst[i] = 0.0f;

    __syncthreads();                       // all staging visible

    float xr1 = 0.f, xr2 = 0.f;
    for (int t = 0; t < T_DIM; ++t) {
        // prefetch x_{t+1} early (latency hides under MFMA phase)
        if (t + 1 < T_DIM) {
            xr1 = x[gb1 + (size_t)(t + 1) * I_DIM];
            if (v2) xr2 = x[gb2 + (size_t)(t + 1) * I_DIM];
        }
        // ---- y_{t-1} = h_{t-1} @ W_out^T (waves 0..7, one 16x16 tile each) ----
        if (t > 0 && w < 8) {
            f32x4 ya = {0.f, 0.f, 0.f, 0.f};
            int arow = ymt * 16 + l15;
            #pragma unroll
            for (int kk = 0; kk < 4; ++kk) {
                unsigned aoff = (unsigned)(arow * 256 + ((((kk << 6) | (q << 4))) ^ ((arow & 7) << 4)));
                bf16x8 a = *(const bf16x8*)(Hl + aoff);
                bf16x8 b = *(const bf16x8*)(WoF + (((ynt * 4 + kk)) << 10) + lane * 16);
                ya = __builtin_amdgcn_mfma_f32_16x16x32_bf16(a, b, ya, 0, 0, 0);
            }
            if (ynt == 0 || l15 == 0) {
                int col = ynt * 16 + l15;
                #pragma unroll
                for (int r = 0; r < 4; ++r) {
                    int row = ymt * 16 + q * 4 + r;
                    out[((size_t)(b0 + row) * T_DIM + (t - 1)) * I_DIM + col] = ya[r] + ybo;
                }
            }
        }
        // ---- gates: acc[mtl][g] over rows (mth*2+mtl)*16.., cols g*128+wg*32+half*16.. ----
        f32x4 acc[2][4];
        #pragma unroll
        for (int mtl = 0; mtl < 2; ++mtl)
            #pragma unroll
            for (int g = 0; g < 4; ++g)
                acc[mtl][g] = (f32x4){bias[g], bias[g], bias[g], bias[g]};

        #pragma unroll
        for (int kk = 0; kk < 4; ++kk) {
            bf16x8 bf[4];
            unsigned fb = ((unsigned)(((wg * 2 + half) * 4 + kk) * 4) << 10) + lane * 16;
            #pragma unroll
            for (int g = 0; g < 4; ++g)
                bf[g] = *(const bf16x8*)(WhF + fb + (g << 10));
            #pragma unroll
            for (int mtl = 0; mtl < 2; ++mtl) {
                int arow = (mth * 2 + mtl) * 16 + l15;
                unsigned aoff = (unsigned)(arow * 256 + ((((kk << 6) | (q << 4))) ^ ((arow & 7) << 4)));
                bf16x8 a = *(const bf16x8*)(Hl + aoff);
                #pragma unroll
                for (int g = 0; g < 4; ++g)
                    acc[mtl][g] = __builtin_amdgcn_mfma_f32_16x16x32_bf16(a, bf[g], acc[mtl][g], 0, 0, 0);
            }
        }
        // x-projection K-step (K=32 zero-padded)
        #pragma unroll
        for (int mtl = 0; mtl < 2; ++mtl) {
            int arow = (mth * 2 + mtl) * 16 + l15;
            bf16x8 a = *(const bf16x8*)(Xl + arow * 80 + q * 16);
            #pragma unroll
            for (int g = 0; g < 4; ++g)
                acc[mtl][g] = __builtin_amdgcn_mfma_f32_16x16x32_bf16(a, wih[g], acc[mtl][g], 0, 0, 0);
        }
        // ---- elementwise cell update (c fp32 in registers) ----
        unsigned hvp[4];
        #pragma unroll
        for (int mtl = 0; mtl < 2; ++mtl) {
            unsigned short hs[4];
            #pragma unroll
            for (int r = 0; r < 4; ++r) {
                float ig = acc[mtl][0][r], fg = acc[mtl][1][r];
                float gg = acc[mtl][2][r], og = acc[mtl][3][r];
                float c  = sigm(fg) * cst[mtl * 4 + r] + sigm(ig) * tanh_(gg);
                cst[mtl * 4 + r] = c;
                hs[r] = f2bf(sigm(og) * tanh_(c));
            }
            hvp[mtl * 2 + 0] = (unsigned)hs[0] | ((unsigned)hs[1] << 16);
            hvp[mtl * 2 + 1] = (unsigned)hs[2] | ((unsigned)hs[3] << 16);
        }
        __syncthreads();   // everyone done reading h_{t-1} and x_t
        // ---- write h_t ----
        {
            int col2 = (wg * 32 + half * 16 + l15) * 2;
            #pragma unroll
            for (int mtl = 0; mtl < 2; ++mtl)
                #pragma unroll
                for (int r = 0; r < 4; ++r) {
                    int row = (mth * 2 + mtl) * 16 + q * 4 + r;
                    unsigned off = (unsigned)(row * 256 + (col2 ^ ((row & 7) << 4)));
                    unsigned vv = hvp[mtl * 2 + (r >> 1)];
                    *(unsigned short*)(Hl + off) = (unsigned short)((r & 1) ? (vv >> 16) : vv);
                }
        }
        // ---- stage x_{t+1} (from prefetch regs) ----
        if (t + 1 < T_DIM) {
            *(unsigned short*)(Xl + lo1) = f2bf(xr1);
            if (v2) *(unsigned short*)(Xl + lo2) = f2bf(xr2);
        }
        __syncthreads();
    }
    // ---- epilogue: y_{T-1} ----
    if (w < 8) {
        f32x4 ya = {0.f, 0.f, 0.f, 0.f};
        int arow = ymt * 16 + l15;
        #pragma unroll
        for (int kk = 0; kk < 4; ++kk) {
            unsigned aoff = (unsigned)(arow * 256 + ((((kk << 6) | (q << 4))) ^ ((arow & 7) << 4)));
            bf16x8 a = *(const bf16x8*)(Hl + aoff);
            bf16x8 b = *(const bf16x8*)(WoF + (((ynt * 4 + kk)) << 10) + lane * 16);
            ya = __builtin_amdgcn_mfma_f32_16x16x32_bf16(a, b, ya, 0, 0, 0);
        }
        if (ynt == 0 || l15 == 0) {
            int col = ynt * 16 + l15;
            #pragma unroll
            for (int r = 0; r < 4; ++r) {
                int row = ymt * 16 + q * 4 + r;
                out[((size_t)(b0 + row) * T_DIM + (T_DIM - 1)) * I_DIM + col] = ya[r] + ybo;
            }
        }
    }
}

extern "C" void kernel_launch(void* const* d_in, const int* in_sizes, int n_in,
                              void* d_out, int out_size, void* d_ws, size_t ws_size,
                              hipStream_t stream) {
    const float* x     = (const float*)d_in[0];
    const float* W_ih  = (const float*)d_in[1];
    const float* W_hh  = (const float*)d_in[2];
    const float* b_ih  = (const float*)d_in[3];
    const float* b_hh  = (const float*)d_in[4];
    const float* W_out = (const float*)d_in[5];
    const float* b_out = (const float*)d_in[6];
    float* out = (float*)d_out;

    dim3 grid(B_DIM / M_ROWS), block(NTHR);
    flowlstm<<<grid, block, 0, stream>>>(x, W_ih, W_hh, b_ih, b_hh, W_out, b_out, out);
}